// Round 1
// baseline (147.037 us; speedup 1.0000x reference)
//
#include <hip/hip_runtime.h>

// PerturbedTopK: B=32, N=500, D=1024, K=16, sigma=0.05
// out[b, rank, idx] += 1/N for each sample's top-K (rank = ascending-index order).

#define PTK_K     16
#define PTK_N     500
#define PTK_B     32
#define PTK_D     1024
#define PTK_SIGMA 0.05f

__global__ __launch_bounds__(256) void ptk_kernel(const float* __restrict__ x,
                                                  const float* __restrict__ noise,
                                                  float* __restrict__ out) {
    const int lane = threadIdx.x & 63;
    const int wv   = threadIdx.x >> 6;
    const int s    = blockIdx.x * 4 + wv;      // sample id, 0..B*N-1 (grid exact)
    const int b    = s / PTK_N;

    const float4* nz = (const float4*)(noise + (size_t)s * PTK_D);
    const float4* xr = (const float4*)(x + (size_t)b * PTK_D);

    // Each lane owns 16 elements: global index g = (c<<8) | (lane<<2) | j
    float v[16];
#pragma unroll
    for (int c = 0; c < 4; ++c) {
        float4 n4 = nz[c * 64 + lane];
        float4 x4 = xr[c * 64 + lane];
        // mul-then-add, unfused, to bit-match the numpy fp32 reference
        v[c * 4 + 0] = __fadd_rn(x4.x, __fmul_rn(n4.x, PTK_SIGMA));
        v[c * 4 + 1] = __fadd_rn(x4.y, __fmul_rn(n4.y, PTK_SIGMA));
        v[c * 4 + 2] = __fadd_rn(x4.z, __fmul_rn(n4.z, PTK_SIGMA));
        v[c * 4 + 3] = __fadd_rn(x4.w, __fmul_rn(n4.w, PTK_SIGMA));
    }

    int myidx = 0;  // lane t (t<K) will hold the t-th extracted (by value) index
    for (int t = 0; t < PTK_K; ++t) {
        // local argmax over the 16 register elements; ascending i == ascending
        // global index, strict '>' keeps the lowest index on (improbable) ties
        float best = v[0];
        int   bl   = 0;
#pragma unroll
        for (int i = 1; i < 16; ++i) {
            if (v[i] > best) { best = v[i]; bl = i; }
        }
        int bg = ((bl >> 2) << 8) | (lane << 2) | (bl & 3);

        // wave-wide argmax, tie-break lower global index
#pragma unroll
        for (int off = 32; off; off >>= 1) {
            float ov = __shfl_xor(best, off, 64);
            int   og = __shfl_xor(bg, off, 64);
            if (ov > best || (ov == best && og < bg)) { best = ov; bg = og; }
        }

        // mask the winner's element to -inf (unrolled -> cndmask, no scratch)
#pragma unroll
        for (int i = 0; i < 16; ++i) {
            int g = ((i >> 2) << 8) | (lane << 2) | (i & 3);
            if (g == bg) v[i] = -__builtin_inff();
        }

        if (lane == t) myidx = bg;
    }

    // rank = position after ascending index sort (indices are distinct)
    int rank = 0;
#pragma unroll
    for (int m = 0; m < PTK_K; ++m) {
        int other = __shfl(myidx, m, 64);
        rank += (other < myidx) ? 1 : 0;
    }

    if (lane < PTK_K) {
        atomicAdd(out + ((size_t)b * PTK_K + rank) * PTK_D + myidx,
                  1.0f / (float)PTK_N);
    }
}

extern "C" void kernel_launch(void* const* d_in, const int* in_sizes, int n_in,
                              void* d_out, int out_size, void* d_ws, size_t ws_size,
                              hipStream_t stream) {
    const float* x     = (const float*)d_in[0];
    const float* noise = (const float*)d_in[1];
    float*       out   = (float*)d_out;

    // harness poisons d_out with 0xAA before every timed launch
    hipMemsetAsync(out, 0, (size_t)out_size * sizeof(float), stream);

    const int samples = PTK_B * PTK_N;          // 16000
    const int blocks  = samples / 4;            // 4 waves (samples) per block
    ptk_kernel<<<blocks, 256, 0, stream>>>(x, noise, out);
}

// Round 2
// 122.356 us; speedup vs baseline: 1.2017x; 1.2017x over previous
//
#include <hip/hip_runtime.h>

// PerturbedTopK: B=32, N=500, D=1024, K=16, sigma=0.05
// out[b, rank, idx] += 1/N for each sample's top-K (rank = ascending-index order).
//
// R2 algorithm (per sample = one wave):
//   1. perturb: v = x + 0.05*noise (unfused, bit-matches numpy)
//   2. bisect threshold T so that 16 <= m = count(v > T) <= 64
//      (ballot + scalar popcount -> ~6 uniform iterations)
//   3. compact the m candidates (val,idx) to LDS via mbcnt prefix
//   4. 64-lane bitonic sort desc by (val, idx-asc tiebreak) -> top-16 in lanes 0..15
//   5. rank = position of idx among the 16 sorted-ascending indices; one atomicAdd

#define PTK_K     16
#define PTK_N     500
#define PTK_B     32
#define PTK_D     1024
#define PTK_SIGMA 0.05f

__global__ __launch_bounds__(256) void ptk_kernel(const float* __restrict__ x,
                                                  const float* __restrict__ noise,
                                                  float* __restrict__ out) {
    const int lane = threadIdx.x & 63;
    const int wv   = threadIdx.x >> 6;
    const int s    = blockIdx.x * 4 + wv;      // sample id (grid exact: 4000*4)
    const int b    = s / PTK_N;

    const float4* nz = (const float4*)(noise + (size_t)s * PTK_D);
    const float4* xr = (const float4*)(x + (size_t)b * PTK_D);

    // Each lane owns 16 elements: global index g = (i>>2)<<8 | lane<<2 | (i&3)
    float v[16];
#pragma unroll
    for (int c = 0; c < 4; ++c) {
        float4 n4 = nz[c * 64 + lane];
        float4 x4 = xr[c * 64 + lane];
        // mul-then-add, unfused, to bit-match the numpy fp32 reference
        v[c * 4 + 0] = __fadd_rn(x4.x, __fmul_rn(n4.x, PTK_SIGMA));
        v[c * 4 + 1] = __fadd_rn(x4.y, __fmul_rn(n4.y, PTK_SIGMA));
        v[c * 4 + 2] = __fadd_rn(x4.z, __fmul_rn(n4.z, PTK_SIGMA));
        v[c * 4 + 3] = __fadd_rn(x4.w, __fmul_rn(n4.w, PTK_SIGMA));
    }

    // ---- 2. bisect for T with 16 <= count(v > T) <= 64 ----
    // |v| < 5 guaranteed (Gaussian data), so [-16,16] brackets everything.
    float lo = -16.0f, hi = 16.0f;
    float T = 0.0f;
    int   m = 0;
    for (int it = 0; it < 64; ++it) {
        T = 0.5f * (lo + hi);
        int cnt = 0;
#pragma unroll
        for (int i = 0; i < 16; ++i)
            cnt += __popcll(__ballot(v[i] > T));   // wave-uniform scalar count
        m = cnt;
        if (cnt >= PTK_K && cnt <= 64) break;
        if (cnt > 64) lo = T; else hi = T;
    }

    // ---- 3. compact candidates (val > T) into LDS, wave-local ----
    __shared__ float cv[4][64];
    __shared__ int   ci[4][64];
    int base = 0;
#pragma unroll
    for (int i = 0; i < 16; ++i) {
        bool p = v[i] > T;
        unsigned long long ball = __ballot(p);
        unsigned int blo = (unsigned int)ball, bhi = (unsigned int)(ball >> 32);
        int before = __builtin_amdgcn_mbcnt_hi(bhi, __builtin_amdgcn_mbcnt_lo(blo, 0u));
        int pos = base + before;
        if (p && pos < 64) {
            cv[wv][pos] = v[i];
            ci[wv][pos] = ((i >> 2) << 8) | (lane << 2) | (i & 3);
        }
        base += __popcll(ball);
    }
    __syncthreads();

    float val = (lane < m) ? cv[wv][lane] : -__builtin_inff();
    int   idx = (lane < m) ? ci[wv][lane] : 0x7fffffff;

    // ---- 4. 64-lane bitonic sort, descending by (val, lower-idx-wins) ----
#pragma unroll
    for (int k = 2; k <= 64; k <<= 1) {
#pragma unroll
        for (int j = k >> 1; j > 0; j >>= 1) {
            float ov = __shfl_xor(val, j, 64);
            int   oi = __shfl_xor(idx, j, 64);
            bool lower = (lane & j) == 0;
            bool descR = (lane & k) == 0;
            bool otherBeats = (ov > val) || (ov == val && oi < idx);
            if (otherBeats == (lower == descR)) { val = ov; idx = oi; }
        }
    }

    // ---- 5. rank among the top-16 by ascending index; scatter ----
    int rank = 0;
#pragma unroll
    for (int t = 0; t < PTK_K; ++t) {
        int oidx = __shfl(idx, t, 64);
        rank += (oidx < idx) ? 1 : 0;
    }
    if (lane < PTK_K) {
        atomicAdd(out + ((size_t)b * PTK_K + rank) * PTK_D + idx,
                  1.0f / (float)PTK_N);
    }
}

extern "C" void kernel_launch(void* const* d_in, const int* in_sizes, int n_in,
                              void* d_out, int out_size, void* d_ws, size_t ws_size,
                              hipStream_t stream) {
    const float* x     = (const float*)d_in[0];
    const float* noise = (const float*)d_in[1];
    float*       out   = (float*)d_out;

    // harness poisons d_out with 0xAA before every timed launch
    hipMemsetAsync(out, 0, (size_t)out_size * sizeof(float), stream);

    const int samples = PTK_B * PTK_N;          // 16000
    const int blocks  = samples / 4;            // 4 waves (samples) per block
    ptk_kernel<<<blocks, 256, 0, stream>>>(x, noise, out);
}